// Round 3
// baseline (202.692 us; speedup 1.0000x reference)
//
#include <hip/hip_runtime.h>
#include <stdint.h>

// Haar 3D DWT: float32 in, float32 out, fp32 internal math.
// x: (2,3,16,256,256) f32
// out: LLL (2,3,15,256,256) followed by detail (2,3,105,256,256), f32.
// detail frame-axis order: LLH, LHL, LHH, HLL, HLH, HHL, HHH (15 frames each).

static constexpr float S = 0.35355339059327373f;  // 1/(2*sqrt(2))
static constexpr int   PLANE = 256 * 256;          // 65536
static constexpr size_t LLL_ELEMS = (size_t)6 * 15 * PLANE;  // 5,898,240

__device__ __forceinline__ float4 pack_lo(const float* A) {
    // width low-pass: S*(A[j] + A[j+1])
    return make_float4(S * (A[0] + A[1]), S * (A[1] + A[2]),
                       S * (A[2] + A[3]), S * (A[3] + A[4]));
}

__device__ __forceinline__ float4 pack_hi(const float* A) {
    // width high-pass: S*(A[j+1] - A[j])
    return make_float4(S * (A[1] - A[0]), S * (A[2] - A[1]),
                       S * (A[3] - A[2]), S * (A[4] - A[3]));
}

__global__ __launch_bounds__(256) void haar3d_kernel(const float* __restrict__ x,
                                                     float* __restrict__ out) {
    const int tid  = blockIdx.x * 256 + threadIdx.x;
    const int lane = threadIdx.x & 63;
    const int row  = tid >> 6;        // 0..23039 : (nc, f, h)
    const int h    = row & 255;
    const int t    = row >> 8;        // 0..89
    const int f    = t % 15;
    const int nc   = t / 15;          // 0..5  (n*3 + c)
    const int w    = lane << 2;

    // ---- loads: 4 rows of float4 (16B/lane, fully coalesced per wave) ----
    const float* p00 = x + ((size_t)(nc * 16 + f) * 256 + h) * 256 + w;
    const float4 z4 = make_float4(0.f, 0.f, 0.f, 0.f);
    float4 v00 = *(const float4*)(p00);            // (f,   h)
    float4 v10 = *(const float4*)(p00 + PLANE);    // (f+1, h)
    float4 v01 = z4, v11 = z4;                     // (*, h+1); zero-pad at h=255
    if (h < 255) {
        v01 = *(const float4*)(p00 + 256);
        v11 = *(const float4*)(p00 + PLANE + 256);
    }

    const float x00[4] = {v00.x, v00.y, v00.z, v00.w};
    const float x10[4] = {v10.x, v10.y, v10.z, v10.w};
    const float x01[4] = {v01.x, v01.y, v01.z, v01.w};
    const float x11[4] = {v11.x, v11.y, v11.z, v11.w};

    // ---- frames + height stages (fp32) ----
    float LL[5], LH[5], HL[5], HH[5];
#pragma unroll
    for (int j = 0; j < 4; ++j) {
        const float l0 = S * (x00[j] + x10[j]);   // frames low  @ h
        const float l1 = S * (x01[j] + x11[j]);   // frames low  @ h+1
        const float g0 = S * (x10[j] - x00[j]);   // frames high @ h
        const float g1 = S * (x11[j] - x01[j]);   // frames high @ h+1
        LL[j] = S * (l0 + l1);
        LH[j] = S * (l1 - l0);
        HL[j] = S * (g0 + g1);
        HH[j] = S * (g1 - g0);
    }

    // ---- width neighbor (w+4) from lane+1; lane 63 -> right zero pad ----
    const float nLL = __shfl_down(LL[0], 1);
    const float nLH = __shfl_down(LH[0], 1);
    const float nHL = __shfl_down(HL[0], 1);
    const float nHH = __shfl_down(HH[0], 1);
    const bool last = (lane == 63);
    LL[4] = last ? 0.f : nLL;
    LH[4] = last ? 0.f : nLH;
    HL[4] = last ? 0.f : nHL;
    HH[4] = last ? 0.f : nHH;

    // ---- width stage + stores (8 coalesced float4 stores/lane) ----
    const size_t rowOff = ((size_t)h) * 256 + w;
    float* lllDst = out + ((size_t)(nc * 15 + f)) * PLANE + rowOff;
    *(float4*)lllDst = pack_lo(LL);                                   // LLL

    float* dbase = out + LLL_ELEMS +
                   ((size_t)nc * 105 + f) * PLANE + rowOff;
    const size_t kStride = (size_t)15 * PLANE;
    *(float4*)(dbase + 0 * kStride) = pack_hi(LL);   // LLH
    *(float4*)(dbase + 1 * kStride) = pack_lo(LH);   // LHL
    *(float4*)(dbase + 2 * kStride) = pack_hi(LH);   // LHH
    *(float4*)(dbase + 3 * kStride) = pack_lo(HL);   // HLL
    *(float4*)(dbase + 4 * kStride) = pack_hi(HL);   // HLH
    *(float4*)(dbase + 5 * kStride) = pack_lo(HH);   // HHL
    *(float4*)(dbase + 6 * kStride) = pack_hi(HH);   // HHH
}

extern "C" void kernel_launch(void* const* d_in, const int* in_sizes, int n_in,
                              void* d_out, int out_size, void* d_ws, size_t ws_size,
                              hipStream_t stream) {
    const float* x = (const float*)d_in[0];
    float* out = (float*)d_out;
    // 23040 rows * 64 lanes = 1,474,560 threads = 5760 blocks of 256 (exact)
    haar3d_kernel<<<dim3(5760), dim3(256), 0, stream>>>(x, out);
}